// Round 4
// baseline (106.782 us; speedup 1.0000x reference)
//
#include <hip/hip_runtime.h>
#include <math.h>

#define FF 4096
#define NPAIR 2048
#define BB 32
#define CC 512
#define NEWF 3073   // int(1 + 4096*0.75)

typedef float f32x4 __attribute__((ext_vector_type(4)));

// ---------------------------------------------------------------------------
// Kernel A: pred[b][f2][{0,1}] = dot(x[2*f2,b,:], W[o,:]) + bias[o]  (fp64)
// One wave per (f2,b) row; 4 waves/block.
// ---------------------------------------------------------------------------
__global__ __launch_bounds__(256) void pred_kernel(
    const float* __restrict__ x, const float* __restrict__ W,
    const float* __restrict__ bias, double* __restrict__ pred) {
  int wave = threadIdx.x >> 6;
  int lane = threadIdx.x & 63;
  int row  = blockIdx.x * 4 + wave;        // row in [0, NPAIR*BB)
  int f2 = row >> 5;                        // / BB
  int b  = row & 31;
  const float* xr = x + ((size_t)(2 * f2) * BB + b) * CC;

  double s0 = 0.0, s1 = 0.0;
#pragma unroll
  for (int k = 0; k < 2; ++k) {
    int c = lane * 4 + k * 256;
    f32x4 xv = __builtin_nontemporal_load((const f32x4*)(xr + c));
    f32x4 w0 = *(const f32x4*)(W + c);
    f32x4 w1 = *(const f32x4*)(W + CC + c);
    s0 += (double)xv.x * (double)w0.x + (double)xv.y * (double)w0.y +
          (double)xv.z * (double)w0.z + (double)xv.w * (double)w0.w;
    s1 += (double)xv.x * (double)w1.x + (double)xv.y * (double)w1.y +
          (double)xv.z * (double)w1.z + (double)xv.w * (double)w1.w;
  }
#pragma unroll
  for (int off = 32; off; off >>= 1) {
    s0 += __shfl_down(s0, off, 64);
    s1 += __shfl_down(s1, off, 64);
  }
  if (lane == 0) {
    size_t o = ((size_t)b * NPAIR + f2) * 2;
    pred[o + 0] = s0 + (double)bias[0];
    pred[o + 1] = s1 + (double)bias[1];
  }
}

// ---------------------------------------------------------------------------
// Kernel C: per-b std, keep decisions, cumsum scan, per-slot contributor
// records, new_lengths, seq_losses, tail sep count. One block (1024 thr) per b.
// rec bits: 0 valid | 1 two-contrib | 2 scale-half | 3 sep | frame<<4
// ---------------------------------------------------------------------------
__global__ __launch_bounds__(1024) void scan_kernel(
    const double* __restrict__ pred, const float* __restrict__ rand_u,
    const int* __restrict__ lengths, int* __restrict__ rec,
    int* __restrict__ tail, float* __restrict__ out_tail) {
  int b = blockIdx.x;
  int t = threadIdx.x;
  int lane = t & 63, wid = t >> 6;          // 16 waves

  __shared__ double wdbl[16];
  __shared__ int    wint[16];
  __shared__ double s_invs;

  int len = lengths[b];
  const double* pb = pred + (size_t)b * NPAIR * 2;

  // two pairs per thread: pr0 = 2t, pr1 = 2t+1; hoist all global loads
  int pr0 = 2 * t, pr1 = 2 * t + 1;
  double2 a0 = ((const double2*)pb)[2 * t];
  double2 a1 = ((const double2*)pb)[2 * t + 1];
  float ru0 = rand_u[(size_t)pr0 * BB + b];
  float ru1 = rand_u[(size_t)pr1 * BB + b];
  double d0 = a0.x - a0.y;
  double d1 = a1.x - a1.y;

  // ---- std over frame axis (fp64) ----
  double sumsq = 0.25 * (d0 * d0 + d1 * d1);
#pragma unroll
  for (int off = 32; off; off >>= 1) sumsq += __shfl_down(sumsq, off, 64);
  if (lane == 0) wdbl[wid] = sumsq;
  __syncthreads();
  if (t == 0) {
    double s = 0;
#pragma unroll
    for (int i = 0; i < 16; ++i) s += wdbl[i];
    s_invs = -3.0 / sqrt(s / (double)NPAIR + 1e-20);
  }
  __syncthreads();
  double si = s_invs;

  // ---- decisions ----
  double prob0 = 1.0 / (1.0 + exp(-d0 * si));
  double prob1 = 1.0 / (1.0 + exp(-d1 * si));
  bool kept0 = prob0 > (double)ru0;
  bool kept1 = prob1 > (double)ru1;
  bool oe0 = (2 * pr0 < len) && kept0;
  bool oo0 = (2 * pr0 + 1) < len;
  bool oe1 = (2 * pr1 < len) && kept1;
  bool oo1 = (2 * pr1 + 1) < len;
  int cnt = (int)oe0 + (int)oo0 + (int)oe1 + (int)oo1;

  // ---- inclusive scan of cnt: wave shfl scan + cross-wave combine ----
  int sc = cnt;
#pragma unroll
  for (int off = 1; off < 64; off <<= 1) {
    int v = __shfl_up(sc, off, 64);
    if (lane >= off) sc += v;
  }
  if (lane == 63) wint[wid] = sc;
  __syncthreads();
  int wprefix = 0, total = 0;
#pragma unroll
  for (int i = 0; i < 16; ++i) {
    int wv = wint[i];
    if (i < wid) wprefix += wv;
    total += wv;
  }
  int base = wprefix + sc - cnt;

  // ---- zero only the empty tail of this b's rec row ----
  // Every slot in [0, min(total,NEWF)) receives exactly one record below;
  // the boundary record (if any) lands at slot == total and is written
  // after this zeroing (post-barrier), so overwrite order is safe.
  int* rrow = rec + (size_t)b * NEWF;
  int zstart = total < NEWF ? total : NEWF;
  for (int s = zstart + t; s < NEWF; s += 1024) rrow[s] = 0;
  __syncthreads();

  // ---- write slot records ----
  int excl = base;
  int tailc = 0;
  double seq = (kept0 ? a0.x : a0.y) + (kept1 ? a1.x : a1.y);

#pragma unroll
  for (int i = 0; i < 2; ++i) {
    int pr = 2 * t + i;
    bool kept = i ? kept1 : kept0;
    bool oe = i ? oe1 : oe0;
    bool oo = i ? oo1 : oo0;
    int fe = 2 * pr, fo = fe + 1;
    int excl_e = excl; excl += (int)oe;
    int excl_o = excl; excl += (int)oo;

    if (oe) {
      if (excl_e < NEWF) {
        int half = oo ? 0 : 1;               // pair_mean 1.0 or 0.5
        rrow[excl_e] = 1 | (half << 2) | (1 << 3) | (fe << 4);
      }
      if (excl_e >= NEWF - 1) tailc++;       // kept in-length even, clamped sep
    }
    if (oo) {
      if (excl_o < NEWF) {
        int two  = kept ? 0 : 1;
        int half = kept ? 0 : 1;
        rrow[excl_o] = 1 | (two << 1) | (half << 2) | ((kept ? 1 : 0) << 3) | (fo << 4);
      }
      if (kept && excl_o >= NEWF - 1) tailc++;  // kept in-length odd, clamped sep
    }
    // boundary: odd past length, even partner kept -> 0.5-scaled contributor
    if (!oo && oe && excl_o < NEWF) {
      rrow[excl_o] = 1 | (1 << 2) | (fo << 4);
    }
  }

  // ---- reduce seq_losses and tail count ----
#pragma unroll
  for (int off = 32; off; off >>= 1) {
    seq   += __shfl_down(seq, off, 64);
    tailc += __shfl_down(tailc, off, 64);
  }
  __syncthreads();          // wdbl/wint reuse
  if (lane == 0) { wdbl[wid] = seq; wint[wid] = tailc; }
  __syncthreads();
  if (t == 0) {
    double ss = 0; int tc = 0;
#pragma unroll
    for (int i = 0; i < 16; ++i) { ss += wdbl[i]; tc += wint[i]; }
    tail[b] = tc;
    out_tail[b]      = (float)(total < NEWF ? total : NEWF);  // new_lengths
    out_tail[BB + b] = (float)ss;                             // seq_losses
  }
}

// ---------------------------------------------------------------------------
// Kernel D: gather. 256 threads = 2 consecutive rows (b fastest), so
// concurrent blocks write one contiguous window of y (DRAM page locality).
// y[s,b,c] = scale*x[f,b,c] (+0.5*x[f-1,b,c] if two) + sep_cnt*is_sep[c]
// ---------------------------------------------------------------------------
__global__ __launch_bounds__(256) void gather_kernel(
    const float* __restrict__ x, const int* __restrict__ rec,
    const int* __restrict__ tail, const float* __restrict__ is_sep,
    float* __restrict__ y) {
  int row = blockIdx.x * 2 + (threadIdx.x >> 7);   // row = s*BB + b
  int s = row >> 5;
  int b = row & 31;
  int c = (threadIdx.x & 127) * 4;

  int r = rec[(size_t)b * NEWF + s];
  int cv = (s == NEWF - 1) ? tail[b] : ((r >> 3) & 1);

  f32x4 acc = (f32x4)(0.f);
  if (r & 1) {
    int f = r >> 4;
    float sc = (r & 4) ? 0.5f : 1.0f;
    f32x4 xv = __builtin_nontemporal_load((const f32x4*)(x + ((size_t)f * BB + b) * CC + c));
    acc = sc * xv;
    if (r & 2) {
      f32x4 x2 = __builtin_nontemporal_load((const f32x4*)(x + ((size_t)(f - 1) * BB + b) * CC + c));
      acc += 0.5f * x2;
    }
  }
  if (cv) {
    f32x4 is = *(const f32x4*)(is_sep + c);
    acc += (float)cv * is;
  }
  __builtin_nontemporal_store(acc, (f32x4*)(y + (size_t)row * CC + c));
}

// ---------------------------------------------------------------------------
extern "C" void kernel_launch(void* const* d_in, const int* in_sizes, int n_in,
                              void* d_out, int out_size, void* d_ws, size_t ws_size,
                              hipStream_t stream) {
  (void)in_sizes; (void)n_in; (void)out_size; (void)ws_size;
  const float* x       = (const float*)d_in[0];
  const int*   lengths = (const int*)d_in[1];
  const float* rand_u  = (const float*)d_in[2];
  const float* W       = (const float*)d_in[3];
  const float* bias    = (const float*)d_in[4];
  const float* is_sep  = (const float*)d_in[5];

  float* y = (float*)d_out;
  float* out_tail = y + (size_t)NEWF * BB * CC;   // [new_lengths(32), seq_losses(32)]

  char* ws = (char*)d_ws;
  double* pred = (double*)ws;                                  // 1 MB
  int* rec  = (int*)(ws + (size_t)BB * NPAIR * 2 * sizeof(double));
  int* tail = rec + (size_t)BB * NEWF;

  pred_kernel<<<(NPAIR * BB) / 4, 256, 0, stream>>>(x, W, bias, pred);
  scan_kernel<<<BB, 1024, 0, stream>>>(pred, rand_u, lengths, rec, tail, out_tail);
  gather_kernel<<<(NEWF * BB) / 2, 256, 0, stream>>>(x, rec, tail, is_sep, y);
}

// Round 5
// 74.984 us; speedup vs baseline: 1.4241x; 1.4241x over previous
//
#include <hip/hip_runtime.h>
#include <math.h>

#define FF 4096
#define NPAIR 2048
#define BB 32
#define CC 512
#define NEWF 3073   // int(1 + 4096*0.75)

typedef float f32x4 __attribute__((ext_vector_type(4)));

// ---------------------------------------------------------------------------
// Kernel A: pred[b][f2][{0,1}] = dot(x[2*f2,b,:], W[o,:]) + bias[o]  (fp64)
// One wave per (f2,b) row; 4 waves/block. Plain loads: fill L3 so gather
// can re-hit the even frames.
// ---------------------------------------------------------------------------
__global__ __launch_bounds__(256) void pred_kernel(
    const float* __restrict__ x, const float* __restrict__ W,
    const float* __restrict__ bias, double* __restrict__ pred) {
  int wave = threadIdx.x >> 6;
  int lane = threadIdx.x & 63;
  int row  = blockIdx.x * 4 + wave;        // row in [0, NPAIR*BB)
  int f2 = row >> 5;                        // / BB
  int b  = row & 31;
  const float* xr = x + ((size_t)(2 * f2) * BB + b) * CC;

  double s0 = 0.0, s1 = 0.0;
#pragma unroll
  for (int k = 0; k < 2; ++k) {
    int c = lane * 4 + k * 256;
    f32x4 xv = *(const f32x4*)(xr + c);
    f32x4 w0 = *(const f32x4*)(W + c);
    f32x4 w1 = *(const f32x4*)(W + CC + c);
    s0 += (double)xv.x * (double)w0.x + (double)xv.y * (double)w0.y +
          (double)xv.z * (double)w0.z + (double)xv.w * (double)w0.w;
    s1 += (double)xv.x * (double)w1.x + (double)xv.y * (double)w1.y +
          (double)xv.z * (double)w1.z + (double)xv.w * (double)w1.w;
  }
#pragma unroll
  for (int off = 32; off; off >>= 1) {
    s0 += __shfl_down(s0, off, 64);
    s1 += __shfl_down(s1, off, 64);
  }
  if (lane == 0) {
    size_t o = ((size_t)b * NPAIR + f2) * 2;
    pred[o + 0] = s0 + (double)bias[0];
    pred[o + 1] = s1 + (double)bias[1];
  }
}

// ---------------------------------------------------------------------------
// Kernel C: per-b std, keep decisions, cumsum scan, per-slot contributor
// records, new_lengths, seq_losses, tail sep count. One block (1024 thr) per b.
// rec bits: 0 valid | 1 two-contrib | 2 scale-half | 3 sep | frame<<4
// ---------------------------------------------------------------------------
__global__ __launch_bounds__(1024) void scan_kernel(
    const double* __restrict__ pred, const float* __restrict__ rand_u,
    const int* __restrict__ lengths, int* __restrict__ rec,
    int* __restrict__ tail, float* __restrict__ out_tail) {
  int b = blockIdx.x;
  int t = threadIdx.x;
  int lane = t & 63, wid = t >> 6;          // 16 waves

  __shared__ double wdbl[16];
  __shared__ int    wint[16];
  __shared__ double s_invs;

  int len = lengths[b];
  const double* pb = pred + (size_t)b * NPAIR * 2;

  // two pairs per thread: pr0 = 2t, pr1 = 2t+1; hoist all global loads
  int pr0 = 2 * t, pr1 = 2 * t + 1;
  double2 a0 = ((const double2*)pb)[2 * t];
  double2 a1 = ((const double2*)pb)[2 * t + 1];
  float ru0 = rand_u[(size_t)pr0 * BB + b];
  float ru1 = rand_u[(size_t)pr1 * BB + b];
  double d0 = a0.x - a0.y;
  double d1 = a1.x - a1.y;

  // ---- std over frame axis (fp64) ----
  double sumsq = 0.25 * (d0 * d0 + d1 * d1);
#pragma unroll
  for (int off = 32; off; off >>= 1) sumsq += __shfl_down(sumsq, off, 64);
  if (lane == 0) wdbl[wid] = sumsq;
  __syncthreads();
  if (t == 0) {
    double s = 0;
#pragma unroll
    for (int i = 0; i < 16; ++i) s += wdbl[i];
    s_invs = -3.0 / sqrt(s / (double)NPAIR + 1e-20);
  }
  __syncthreads();
  double si = s_invs;

  // ---- decisions ----
  double prob0 = 1.0 / (1.0 + exp(-d0 * si));
  double prob1 = 1.0 / (1.0 + exp(-d1 * si));
  bool kept0 = prob0 > (double)ru0;
  bool kept1 = prob1 > (double)ru1;
  bool oe0 = (2 * pr0 < len) && kept0;
  bool oo0 = (2 * pr0 + 1) < len;
  bool oe1 = (2 * pr1 < len) && kept1;
  bool oo1 = (2 * pr1 + 1) < len;
  int cnt = (int)oe0 + (int)oo0 + (int)oe1 + (int)oo1;

  // ---- inclusive scan of cnt: wave shfl scan + cross-wave combine ----
  int sc = cnt;
#pragma unroll
  for (int off = 1; off < 64; off <<= 1) {
    int v = __shfl_up(sc, off, 64);
    if (lane >= off) sc += v;
  }
  if (lane == 63) wint[wid] = sc;
  __syncthreads();
  int wprefix = 0, total = 0;
#pragma unroll
  for (int i = 0; i < 16; ++i) {
    int wv = wint[i];
    if (i < wid) wprefix += wv;
    total += wv;
  }
  int base = wprefix + sc - cnt;

  // ---- zero only the empty tail of this b's rec row ----
  int* rrow = rec + (size_t)b * NEWF;
  int zstart = total < NEWF ? total : NEWF;
  for (int s = zstart + t; s < NEWF; s += 1024) rrow[s] = 0;
  __syncthreads();

  // ---- write slot records ----
  int excl = base;
  int tailc = 0;
  double seq = (kept0 ? a0.x : a0.y) + (kept1 ? a1.x : a1.y);

#pragma unroll
  for (int i = 0; i < 2; ++i) {
    int pr = 2 * t + i;
    bool kept = i ? kept1 : kept0;
    bool oe = i ? oe1 : oe0;
    bool oo = i ? oo1 : oo0;
    int fe = 2 * pr, fo = fe + 1;
    int excl_e = excl; excl += (int)oe;
    int excl_o = excl; excl += (int)oo;

    if (oe) {
      if (excl_e < NEWF) {
        int half = oo ? 0 : 1;               // pair_mean 1.0 or 0.5
        rrow[excl_e] = 1 | (half << 2) | (1 << 3) | (fe << 4);
      }
      if (excl_e >= NEWF - 1) tailc++;       // kept in-length even, clamped sep
    }
    if (oo) {
      if (excl_o < NEWF) {
        int two  = kept ? 0 : 1;
        int half = kept ? 0 : 1;
        rrow[excl_o] = 1 | (two << 1) | (half << 2) | ((kept ? 1 : 0) << 3) | (fo << 4);
      }
      if (kept && excl_o >= NEWF - 1) tailc++;  // kept in-length odd, clamped sep
    }
    // boundary: odd past length, even partner kept -> 0.5-scaled contributor
    if (!oo && oe && excl_o < NEWF) {
      rrow[excl_o] = 1 | (1 << 2) | (fo << 4);
    }
  }

  // ---- reduce seq_losses and tail count ----
#pragma unroll
  for (int off = 32; off; off >>= 1) {
    seq   += __shfl_down(seq, off, 64);
    tailc += __shfl_down(tailc, off, 64);
  }
  __syncthreads();          // wdbl/wint reuse
  if (lane == 0) { wdbl[wid] = seq; wint[wid] = tailc; }
  __syncthreads();
  if (t == 0) {
    double ss = 0; int tc = 0;
#pragma unroll
    for (int i = 0; i < 16; ++i) { ss += wdbl[i]; tc += wint[i]; }
    tail[b] = tc;
    out_tail[b]      = (float)(total < NEWF ? total : NEWF);  // new_lengths
    out_tail[BB + b] = (float)ss;                             // seq_losses
  }
}

// ---------------------------------------------------------------------------
// Kernel D: gather. One block per (slot, b); 128 threads x float4 = 512 floats.
// Plain x loads (hit L3 lines pred just fetched); NT store for the y stream.
// y[s,b,c] = scale*x[f,b,c] (+0.5*x[f-1,b,c] if two) + sep_cnt*is_sep[c]
// ---------------------------------------------------------------------------
__global__ __launch_bounds__(128) void gather_kernel(
    const float* __restrict__ x, const int* __restrict__ rec,
    const int* __restrict__ tail, const float* __restrict__ is_sep,
    float* __restrict__ y) {
  int s = blockIdx.x;
  int b = blockIdx.y;
  int r = rec[(size_t)b * NEWF + s];
  int c = threadIdx.x * 4;

  int cv = (s == NEWF - 1) ? tail[b] : ((r >> 3) & 1);

  f32x4 acc = (f32x4)(0.f);
  if (r & 1) {
    int f = r >> 4;
    float sc = (r & 4) ? 0.5f : 1.0f;
    f32x4 xv = *(const f32x4*)(x + ((size_t)f * BB + b) * CC + c);
    acc = sc * xv;
    if (r & 2) {
      f32x4 x2 = *(const f32x4*)(x + ((size_t)(f - 1) * BB + b) * CC + c);
      acc += 0.5f * x2;
    }
  }
  if (cv) {
    f32x4 is = *(const f32x4*)(is_sep + c);
    acc += (float)cv * is;
  }
  __builtin_nontemporal_store(acc, (f32x4*)(y + ((size_t)s * BB + b) * CC + c));
}

// ---------------------------------------------------------------------------
extern "C" void kernel_launch(void* const* d_in, const int* in_sizes, int n_in,
                              void* d_out, int out_size, void* d_ws, size_t ws_size,
                              hipStream_t stream) {
  (void)in_sizes; (void)n_in; (void)out_size; (void)ws_size;
  const float* x       = (const float*)d_in[0];
  const int*   lengths = (const int*)d_in[1];
  const float* rand_u  = (const float*)d_in[2];
  const float* W       = (const float*)d_in[3];
  const float* bias    = (const float*)d_in[4];
  const float* is_sep  = (const float*)d_in[5];

  float* y = (float*)d_out;
  float* out_tail = y + (size_t)NEWF * BB * CC;   // [new_lengths(32), seq_losses(32)]

  char* ws = (char*)d_ws;
  double* pred = (double*)ws;                                  // 1 MB
  int* rec  = (int*)(ws + (size_t)BB * NPAIR * 2 * sizeof(double));
  int* tail = rec + (size_t)BB * NEWF;

  pred_kernel<<<(NPAIR * BB) / 4, 256, 0, stream>>>(x, W, bias, pred);
  scan_kernel<<<BB, 1024, 0, stream>>>(pred, rand_u, lengths, rec, tail, out_tail);
  gather_kernel<<<dim3(NEWF, BB), 128, 0, stream>>>(x, rec, tail, is_sep, y);
}